// Round 3
// baseline (29.788 us; speedup 1.0000x reference)
//
#include <hip/hip_runtime.h>
#include <hip/hip_bf16.h>

#define D_N 512
#define M_N 1024
#define F_N 64
#define L2E 1.442695041f

__device__ __forceinline__ float wred_sum(float p) {
#pragma unroll
    for (int off = 32; off > 0; off >>= 1) p += __shfl_xor(p, off, 64);
    return p;
}
__device__ __forceinline__ float wred_max(float p) {
#pragma unroll
    for (int off = 32; off > 0; off >>= 1) p = fmaxf(p, __shfl_xor(p, off, 64));
    return p;
}

// ---------------------------------------------------------------------------
// k_pre: blocks 0..47   : partial gathers (P0/MC over c_it, P1/MM over m_it)
//        blocks 48..431 : xw[n] = comb[n]@gat_w.T, u[n] = L2E*(xw[n].att1)
//        block 48 wave 0: w2[j] = sum_k att2[k]*gat_w[k][j]
// pp layout: P0 [0,16), MC [16,32), P1 [32,64), MM [64,96)  (each x64)
// ---------------------------------------------------------------------------
__global__ __launch_bounds__(256) void k_pre(
    const int* __restrict__ c_it, const int* __restrict__ m_it,
    const float* __restrict__ c_emb, const float* __restrict__ m_emb,
    const float* __restrict__ pe0, const float* __restrict__ pe1,
    const float* __restrict__ gat_w, const float* __restrict__ gat_att,
    float* __restrict__ xw, float* __restrict__ u, float* __restrict__ w2,
    float* __restrict__ pp)
{
    __shared__ float sWt[64 * 65];
    __shared__ float sX[4][64];
    __shared__ float redA[4][64], redB[4][64];
    const int tid = threadIdx.x;
    const int w = tid >> 6, lane = tid & 63;
    const int b = blockIdx.x;

    if (b < 48) {
        const int* idx; const float* ta; const float* tb;
        int base, outA, outB;
        if (b < 16) { idx = c_it; ta = pe0; tb = c_emb; base = b * 32; outA = b; outB = 16 + b; }
        else { int b2 = b - 16; idx = m_it; ta = pe1; tb = m_emb; base = b2 * 32; outA = 32 + b2; outB = 64 + b2; }
        const int r0 = base + w * 8;
        float a = 0.f, bb = 0.f;
#pragma unroll
        for (int j = 0; j < 8; ++j) {
            int r = idx[r0 + j];
            a  += ta[(size_t)r * F_N + lane];
            bb += tb[(size_t)r * F_N + lane];
        }
        redA[w][lane] = a; redB[w][lane] = bb;
        __syncthreads();
        if (w == 0) {
            pp[outA * 64 + lane] = redA[0][lane] + redA[1][lane] + redA[2][lane] + redA[3][lane];
            pp[outB * 64 + lane] = redB[0][lane] + redB[1][lane] + redB[2][lane] + redB[3][lane];
        }
        return;
    }

    const int bx = b - 48;
    for (int idx = tid; idx < 4096; idx += 256) {
        int k = idx >> 6, j = idx & 63;
        sWt[j * 65 + k] = gat_w[idx];      // sWt[j*65+k] = W[k][j]
    }
    const int n = bx * 4 + w;
    const float* xr = (n < D_N) ? (c_emb + (size_t)c_it[n] * F_N)
                                : (m_emb + (size_t)m_it[n - D_N] * F_N);
    sX[w][lane] = xr[lane];
    __syncthreads();
    float acc = 0.f;
#pragma unroll
    for (int j = 0; j < 64; ++j)
        acc += sX[w][j] * sWt[j * 65 + lane];
    xw[n * F_N + lane] = acc;
    float p = wred_sum(acc * gat_att[lane]);
    if (lane == 0) u[n] = p * L2E;         // log2-domain logits
    if (bx == 0 && w == 0) {
        float s = 0.f;
#pragma unroll
        for (int k = 0; k < 64; ++k)
            s += gat_att[64 + k] * sWt[lane * 65 + k];
        w2[lane] = s;
    }
}

// ---------------------------------------------------------------------------
// k_scal: one wave per edge (128 blocks x 4 waves).
//  v = L2E * hattr[e].w2 ; logits a = lrelu(u + v) (log2 domain)
//  bmax, denom (incl self), then per-edge coefficients:
//   c1f = asel /(denom*1025) * 2^-bmax     (med coeff for S1)
//   c2f = (1-asel)/(denom*1025) * 2^-bmax  (med coeff for S2pre)
//   w1a = asel *ex_self/(denom*1025)       (self coeff for S1)
//   w2a = (1-asel)*ex_self/(denom*1025)    (self coeff for S2pre)
// ---------------------------------------------------------------------------
__global__ __launch_bounds__(256) void k_scal(
    const float* __restrict__ hattr, const float* __restrict__ u,
    const float* __restrict__ w2g,
    float* __restrict__ vS, float* __restrict__ c1f, float* __restrict__ c2f,
    float* __restrict__ w1a, float* __restrict__ w2a)
{
    const int tid = threadIdx.x;
    const int w = tid >> 6, lane = tid & 63;
    const int e = blockIdx.x * 4 + w;

    float v = wred_sum(hattr[(size_t)e * F_N + lane] * w2g[lane]) * L2E;

    float mx = -1e30f;
#pragma unroll
    for (int i = 0; i < 16; ++i) {
        float a = u[D_N + lane + i * 64] + v;
        a = fmaxf(a, 0.2f * a);
        mx = fmaxf(mx, a);
    }
    mx = wred_max(mx);
    float a_self = u[e] + v;
    a_self = fmaxf(a_self, 0.2f * a_self);
    const float bmax = fmaxf(mx, a_self);

    float s = 0.f;
#pragma unroll
    for (int i = 0; i < 16; ++i) {
        float a = u[D_N + lane + i * 64] + v;
        a = fmaxf(a, 0.2f * a);
        s += exp2f(a - bmax);
    }
    s = wred_sum(s);
    const float ex_self = exp2f(a_self - bmax);
    const float denom = s + ex_self;
    const float asel = ex_self / denom;
    const float rd = 1.f / (denom * (float)(M_N + 1));
    if (lane == 0) {
        const float ebm = exp2f(-bmax);
        vS[e]  = v;
        c1f[e] = asel * rd * ebm;
        c2f[e] = (1.f - asel) * rd * ebm;
        w1a[e] = asel * rd * ex_self;
        w2a[e] = (1.f - asel) * rd * ex_self;
    }
}

// ---------------------------------------------------------------------------
// k_g: blocks 0..7 : med slice of 128; 2 threads/med split e-range; then
//                    g1[m],g2[m] -> partial matvec over xw_med slice.
//      blocks 8..9 : self terms: partial  sum_e w1a[e]*xw[e], w2a[e]*xw[e].
//  ps[b*128 + k] = partial S1, ps[b*128+64+k] = partial S2pre.
// ---------------------------------------------------------------------------
__global__ __launch_bounds__(256) void k_g(
    const float* __restrict__ u, const float* __restrict__ xw,
    const float* __restrict__ vS, const float* __restrict__ c1f,
    const float* __restrict__ c2f, const float* __restrict__ w1a,
    const float* __restrict__ w2a, float* __restrict__ ps)
{
    __shared__ float sV[512], sC1[512], sC2[512];
    __shared__ float sGA[256], sGB[256];
    __shared__ float red[4][64], red2[4][64];
    const int b = blockIdx.x, tid = threadIdx.x;
    const int w = tid >> 6, lane = tid & 63;

    if (b < 8) {
        for (int i = tid; i < 512; i += 256) {
            sV[i] = vS[i]; sC1[i] = c1f[i]; sC2[i] = c2f[i];
        }
        __syncthreads();
        const int mloc = tid & 127;
        const int eh = tid >> 7;               // e-half: 0 or 1
        const float um = u[D_N + b * 128 + mloc];
        float gA = 0.f, gB = 0.f;
#pragma unroll 4
        for (int i = 0; i < 256; ++i) {
            int e = eh * 256 + i;
            float a = um + sV[e];
            a = fmaxf(a, 0.2f * a);
            float ex = exp2f(a);
            gA += sC1[e] * ex;
            gB += sC2[e] * ex;
        }
        sGA[tid] = gA; sGB[tid] = gB;
        __syncthreads();
        if (tid < 128) { sGA[tid] += sGA[tid + 128]; sGB[tid] += sGB[tid + 128]; }
        __syncthreads();
        // partial matvec: wave w handles meds [w*32, w*32+32) of this slice
        float a1 = 0.f, a2 = 0.f;
        const float* xm = xw + (size_t)(D_N + b * 128 + w * 32) * F_N + lane;
        for (int i = 0; i < 32; ++i) {
            float xv = xm[(size_t)i * F_N];
            a1 += sGA[w * 32 + i] * xv;
            a2 += sGB[w * 32 + i] * xv;
        }
        red[w][lane] = a1; red2[w][lane] = a2;
        __syncthreads();
        if (w == 0) {
            ps[b * 128 + lane]      = red[0][lane] + red[1][lane] + red[2][lane] + red[3][lane];
            ps[b * 128 + 64 + lane] = red2[0][lane] + red2[1][lane] + red2[2][lane] + red2[3][lane];
        }
    } else {
        const int e0 = (b - 8) * 256 + w * 64;
        float a1 = 0.f, a2 = 0.f;
        const float* xe = xw + (size_t)e0 * F_N + lane;
        for (int i = 0; i < 64; ++i) {
            float xv = xe[(size_t)i * F_N];
            a1 += w1a[e0 + i] * xv;
            a2 += w2a[e0 + i] * xv;
        }
        red[w][lane] = a1; red2[w][lane] = a2;
        __syncthreads();
        if (w == 0) {
            ps[b * 128 + lane]      = red[0][lane] + red[1][lane] + red[2][lane] + red[3][lane];
            ps[b * 128 + 64 + lane] = red2[0][lane] + red2[1][lane] + red2[2][lane] + red2[3][lane];
        }
    }
}

// ---------------------------------------------------------------------------
// k_fin: fold partials, matvecs, write 128 floats.
// ---------------------------------------------------------------------------
__global__ __launch_bounds__(256) void k_fin(
    const float* __restrict__ pp, const float* __restrict__ ps,
    const float* __restrict__ conv_w, const float* __restrict__ conv_b,
    const float* __restrict__ gat_b, const float* __restrict__ lin_w,
    float* __restrict__ out)
{
    __shared__ float S1[64], S2[64], P0[64], P1[64], MC[64], MM[64];
    __shared__ float repD[128], repM[128];
    const int tid = threadIdx.x;
    const int w = tid >> 6, lane = tid & 63;
    if (w == 0) {
        float a = 0.f, b = 0.f;
#pragma unroll
        for (int i = 0; i < 16; ++i) { a += pp[i * 64 + lane]; b += pp[(16 + i) * 64 + lane]; }
        P0[lane] = a; MC[lane] = b * (1.f / (float)D_N);
    } else if (w == 1) {
        float a = 0.f, b = 0.f;
#pragma unroll
        for (int i = 0; i < 32; ++i) { a += pp[(32 + i) * 64 + lane]; b += pp[(64 + i) * 64 + lane]; }
        P1[lane] = a; MM[lane] = b * (1.f / (float)M_N);
    } else if (w == 2) {
        float a = 0.f, b = 0.f;
#pragma unroll
        for (int i = 0; i < 10; ++i) { a += ps[i * 128 + lane]; b += ps[i * 128 + 64 + lane]; }
        S1[lane] = a; S2[lane] = b * (1.f / (float)D_N);
    }
    __syncthreads();
    if (tid < 64) {
        float dia = conv_b[lane], med = conv_b[lane];
#pragma unroll 8
        for (int j = 0; j < 64; ++j) {
            dia += MC[j] * conv_w[lane * 64 + j];
            med += MM[j] * conv_w[lane * 64 + j];
        }
        repD[lane]      = S1[lane] + (float)D_N * gat_b[lane];
        repD[64 + lane] = (float)D_N * dia;
        repM[lane]      = S2[lane] + (float)M_N * gat_b[lane];
        repM[64 + lane] = (float)M_N * med;
    }
    __syncthreads();
    if (tid < 64) {
        float o1 = P0[lane], o2 = P1[lane];
#pragma unroll 8
        for (int j = 0; j < 128; ++j) {
            o1 += repD[j] * lin_w[lane * 128 + j];
            o2 += repM[j] * lin_w[lane * 128 + j];
        }
        out[lane] = o1;
        out[64 + lane] = o2;
    }
}

extern "C" void kernel_launch(void* const* d_in, const int* in_sizes, int n_in,
                              void* d_out, int out_size, void* d_ws, size_t ws_size,
                              hipStream_t stream) {
    const int*   c_it    = (const int*)d_in[0];
    const int*   m_it    = (const int*)d_in[1];
    const float* c_emb   = (const float*)d_in[2];
    const float* m_emb   = (const float*)d_in[3];
    const float* pe0     = (const float*)d_in[4];
    const float* pe1     = (const float*)d_in[5];
    const float* conv_w  = (const float*)d_in[6];
    const float* conv_b  = (const float*)d_in[7];
    const float* gat_w   = (const float*)d_in[8];
    const float* gat_b   = (const float*)d_in[9];
    const float* gat_att = (const float*)d_in[10];
    const float* hattr   = (const float*)d_in[11];
    const float* lin_w   = (const float*)d_in[12];
    float* out = (float*)d_out;

    float* ws  = (float*)d_ws;
    float* xw  = ws;                         // 1536*64
    float* u   = xw + (D_N + M_N) * F_N;     // 1536
    float* w2  = u + (D_N + M_N);            // 64
    float* vS  = w2 + 64;                    // 512
    float* c1f = vS + D_N;                   // 512
    float* c2f = c1f + D_N;                  // 512
    float* w1a = c2f + D_N;                  // 512
    float* w2a = w1a + D_N;                  // 512
    float* pp  = w2a + D_N;                  // 96*64
    float* ps  = pp + 96 * 64;               // 10*128

    k_pre<<<48 + (D_N + M_N) / 4, 256, 0, stream>>>(c_it, m_it, c_emb, m_emb,
                                                    pe0, pe1, gat_w, gat_att,
                                                    xw, u, w2, pp);
    k_scal<<<D_N / 4, 256, 0, stream>>>(hattr, u, w2, vS, c1f, c2f, w1a, w2a);
    k_g<<<10, 256, 0, stream>>>(u, xw, vS, c1f, c2f, w1a, w2a, ps);
    k_fin<<<1, 256, 0, stream>>>(pp, ps, conv_w, conv_b, gat_b, lin_w, out);
}